// Round 1
// baseline (2830.920 us; speedup 1.0000x reference)
//
#include <hip/hip_runtime.h>
#include <hip/hip_bf16.h>

// FlashDeepseekLayer: MoE (16 experts, top-4, CAP=1024) + shared SwiGLU.
// Round 0: bf16 MFMA GEMMs (16x16x32), m93-style 128x128 tiles, reg-staged LDS.
// Weights transposed+cast to [N][K] bf16 in workspace so A/B staging is uniform.

#define T_TOK 2048
#define H_DIM 2048
#define E_NUM 16
#define K_TOP 4
#define I_DIM 1408
#define IS_DIM 2816
#define CAP 1024

#define BM 128
#define BN 128
#define BK 32
#define LDT 40  // padded LDS row stride (elements); 80 B = 5*16 B

typedef __attribute__((ext_vector_type(8))) short short8;
typedef __attribute__((ext_vector_type(4))) float floatx4;

__device__ __forceinline__ unsigned short f2bf(float f) {
    union { float f; unsigned u; } v; v.f = f;
    unsigned r = v.u + 0x7FFF + ((v.u >> 16) & 1);   // RNE
    return (unsigned short)(r >> 16);
}

// ---------------- x fp32 -> bf16 (layout preserved) ----------------
__global__ void cvt_x(const float* __restrict__ in, unsigned short* __restrict__ out, int n4) {
    int i = blockIdx.x * 256 + threadIdx.x;
    if (i >= n4) return;
    float4 v = ((const float4*)in)[i];
    ushort4 o;
    o.x = f2bf(v.x); o.y = f2bf(v.y); o.z = f2bf(v.z); o.w = f2bf(v.w);
    ((ushort4*)out)[i] = o;
}

// ---------------- transpose + cast: in [R][C] fp32 -> out [C][R] bf16 ----------------
__global__ void tr_cast(const float* __restrict__ in, unsigned short* __restrict__ out,
                        int R, int C) {
    __shared__ float tile[64][65];
    size_t boff = (size_t)blockIdx.z * R * C;
    in += boff; out += boff;
    int c0 = blockIdx.x * 64, r0 = blockIdx.y * 64;
    int tc = threadIdx.x & 63, tr4 = threadIdx.x >> 6;  // 0..3
    for (int p = 0; p < 16; ++p) {
        int r = tr4 + p * 4;
        tile[r][tc] = in[(size_t)(r0 + r) * C + c0 + tc];
    }
    __syncthreads();
    for (int p = 0; p < 16; ++p) {
        int rw = tr4 + p * 4;  // output row within tile (= original col)
        out[(size_t)(c0 + rw) * R + r0 + tc] = f2bf(tile[tc][rw]);
    }
}

// ---------------- gating: fp32 scores, softmax top-4, atomic dispatch ----------------
__global__ void gate_topk(const float* __restrict__ x, const float* __restrict__ gw,
                          int* __restrict__ counts, int* __restrict__ buf,
                          float* __restrict__ wbuf) {
    int t = blockIdx.x;
    int tid = threadIdx.x, w = tid >> 6, lane = tid & 63;
    __shared__ float sc[E_NUM];
    const float* xr = x + (size_t)t * H_DIM;
    for (int e4 = 0; e4 < 4; ++e4) {
        int e = w * 4 + e4;
        const float* gr = gw + (size_t)e * H_DIM;
        float s = 0.f;
        for (int h = lane; h < H_DIM; h += 64) s += xr[h] * gr[h];
        for (int off = 32; off; off >>= 1) s += __shfl_xor(s, off);
        if (lane == 0) sc[e] = s;
    }
    __syncthreads();
    if (tid == 0) {
        int idx[4]; float lv[4]; unsigned taken = 0;
        for (int k = 0; k < 4; ++k) {
            int bi = 0; float bv = -1e30f;
            for (int e = 0; e < E_NUM; ++e)
                if (!((taken >> e) & 1) && sc[e] > bv) { bv = sc[e]; bi = e; }
            taken |= 1u << bi; idx[k] = bi; lv[k] = bv;
        }
        float m = lv[0], ws[4], s = 0.f;
        for (int k = 0; k < 4; ++k) { ws[k] = expf(lv[k] - m); s += ws[k]; }
        float inv = 1.f / s;
        for (int k = 0; k < 4; ++k) {
            int e = idx[k];
            int r = atomicAdd(&counts[e], 1);
            if (r < CAP) { buf[e * CAP + r] = t; wbuf[e * CAP + r] = ws[k] * inv; }
        }
    }
}

// ---------------- fused gate+up GEMM with SwiGLU epilogue -> bf16 mid ----------------
// A: bf16 [*, K] rows (gathered via buf if non-null). Bg/Bu: bf16 [z][N][K].
// out: bf16 [z][Mrows][N].
__global__ __launch_bounds__(256, 2)
void gemm_gateup(const unsigned short* __restrict__ A,
                 const unsigned short* __restrict__ Bg,
                 const unsigned short* __restrict__ Bu,
                 unsigned short* __restrict__ out,
                 const int* __restrict__ buf, const int* __restrict__ counts,
                 int K, int N, long long outBatchStride) {
    int e = blockIdx.z;
    int col0 = blockIdx.x * BN, row0 = blockIdx.y * BM;
    if (counts) { if (row0 >= counts[e]) return; }
    const unsigned short* bgB = Bg + (size_t)e * N * K;
    const unsigned short* buB = Bu + (size_t)e * N * K;
    unsigned short* outB = out + (size_t)e * outBatchStride;

    __shared__ unsigned short lA[BM * LDT], lG[BM * LDT], lU[BM * LDT];

    int tid = threadIdx.x;
    const unsigned short *ap[2], *gp[2], *up[2];
    int wrOff[2];
    for (int i = 0; i < 2; ++i) {
        int c = tid + i * 256, r = c >> 2, s = c & 3;
        int grow = buf ? buf[e * CAP + row0 + r] : (row0 + r);
        ap[i] = A + (size_t)grow * K + s * 8;
        gp[i] = bgB + (size_t)(col0 + r) * K + s * 8;
        up[i] = buB + (size_t)(col0 + r) * K + s * 8;
        wrOff[i] = r * LDT + s * 8;
    }

    int w = tid >> 6, lane = tid & 63;
    int wm = (w >> 1) * 64, wn = (w & 1) * 64;
    int lq = lane >> 4, lr = lane & 15;

    floatx4 accg[4][4], accu[4][4];
    for (int i = 0; i < 4; ++i)
        for (int j = 0; j < 4; ++j) {
            accg[i][j] = (floatx4){0.f, 0.f, 0.f, 0.f};
            accu[i][j] = (floatx4){0.f, 0.f, 0.f, 0.f};
        }

    for (int k0 = 0; k0 < K; k0 += BK) {
        int4 av[2], gv[2], uv[2];
        for (int i = 0; i < 2; ++i) {
            av[i] = *(const int4*)(ap[i] + k0);
            gv[i] = *(const int4*)(gp[i] + k0);
            uv[i] = *(const int4*)(up[i] + k0);
        }
        __syncthreads();
        for (int i = 0; i < 2; ++i) {
            *(int4*)(lA + wrOff[i]) = av[i];
            *(int4*)(lG + wrOff[i]) = gv[i];
            *(int4*)(lU + wrOff[i]) = uv[i];
        }
        __syncthreads();
        short8 aF[4], gF[4], uF[4];
        for (int i = 0; i < 4; ++i)
            aF[i] = *(const short8*)(lA + (wm + i * 16 + lr) * LDT + lq * 8);
        for (int j = 0; j < 4; ++j) {
            gF[j] = *(const short8*)(lG + (wn + j * 16 + lr) * LDT + lq * 8);
            uF[j] = *(const short8*)(lU + (wn + j * 16 + lr) * LDT + lq * 8);
        }
        for (int i = 0; i < 4; ++i)
            for (int j = 0; j < 4; ++j) {
                accg[i][j] = __builtin_amdgcn_mfma_f32_16x16x32_bf16(aF[i], gF[j], accg[i][j], 0, 0, 0);
                accu[i][j] = __builtin_amdgcn_mfma_f32_16x16x32_bf16(aF[i], uF[j], accu[i][j], 0, 0, 0);
            }
    }
    for (int i = 0; i < 4; ++i) {
        int rbase = row0 + wm + i * 16 + lq * 4;
        for (int j = 0; j < 4; ++j) {
            int col = col0 + wn + j * 16 + lr;
            for (int r = 0; r < 4; ++r) {
                float g = accg[i][j][r], u = accu[i][j][r];
                float mval = g / (1.f + __expf(-g)) * u;  // silu(g)*u
                outB[(size_t)(rbase + r) * N + col] = f2bf(mval);
            }
        }
    }
}

// ---------------- down GEMM: direct store (shared) or scaled atomic scatter (routed) ----
// A: bf16 [z][Mrows][K]. B: bf16 [z][N][K]. y: fp32 [T][N].
__global__ __launch_bounds__(256, 2)
void gemm_down(const unsigned short* __restrict__ A,
               const unsigned short* __restrict__ B,
               float* __restrict__ y,
               const int* __restrict__ buf, const int* __restrict__ counts,
               const float* __restrict__ wbuf,
               int K, int N, long long aBatchStride, long long bBatchStride) {
    int e = blockIdx.z;
    int col0 = blockIdx.x * BN, row0 = blockIdx.y * BM;
    int cnt = 1 << 30;
    if (counts) { cnt = counts[e]; if (row0 >= cnt) return; }
    const unsigned short* aB = A + (size_t)e * aBatchStride;
    const unsigned short* bB = B + (size_t)e * bBatchStride;

    __shared__ unsigned short lA[BM * LDT], lB[BM * LDT];
    __shared__ int sTok[BM];
    __shared__ float sW[BM];

    int tid = threadIdx.x;
    if (buf && tid < BM) {
        sTok[tid] = buf[e * CAP + row0 + tid];
        sW[tid] = wbuf[e * CAP + row0 + tid];
    }

    const unsigned short *ap[2], *bp[2];
    int wrOff[2];
    for (int i = 0; i < 2; ++i) {
        int c = tid + i * 256, r = c >> 2, s = c & 3;
        ap[i] = aB + (size_t)(row0 + r) * K + s * 8;
        bp[i] = bB + (size_t)(col0 + r) * K + s * 8;
        wrOff[i] = r * LDT + s * 8;
    }
    int w = tid >> 6, lane = tid & 63;
    int wm = (w >> 1) * 64, wn = (w & 1) * 64;
    int lq = lane >> 4, lr = lane & 15;

    floatx4 acc[4][4];
    for (int i = 0; i < 4; ++i)
        for (int j = 0; j < 4; ++j) acc[i][j] = (floatx4){0.f, 0.f, 0.f, 0.f};

    for (int k0 = 0; k0 < K; k0 += BK) {
        int4 av[2], bv[2];
        for (int i = 0; i < 2; ++i) {
            av[i] = *(const int4*)(ap[i] + k0);
            bv[i] = *(const int4*)(bp[i] + k0);
        }
        __syncthreads();
        for (int i = 0; i < 2; ++i) {
            *(int4*)(lA + wrOff[i]) = av[i];
            *(int4*)(lB + wrOff[i]) = bv[i];
        }
        __syncthreads();
        short8 aF[4], bF[4];
        for (int i = 0; i < 4; ++i)
            aF[i] = *(const short8*)(lA + (wm + i * 16 + lr) * LDT + lq * 8);
        for (int j = 0; j < 4; ++j)
            bF[j] = *(const short8*)(lB + (wn + j * 16 + lr) * LDT + lq * 8);
        for (int i = 0; i < 4; ++i)
            for (int j = 0; j < 4; ++j)
                acc[i][j] = __builtin_amdgcn_mfma_f32_16x16x32_bf16(aF[i], bF[j], acc[i][j], 0, 0, 0);
    }

    for (int i = 0; i < 4; ++i) {
        int rl = wm + i * 16 + lq * 4;
        for (int j = 0; j < 4; ++j) {
            int col = col0 + wn + j * 16 + lr;
            for (int r = 0; r < 4; ++r) {
                float v = acc[i][j][r];
                if (buf) {
                    int row = row0 + rl + r;
                    if (row < cnt)
                        atomicAdd(&y[(size_t)sTok[rl + r] * N + col], v * sW[rl + r]);
                } else {
                    y[(size_t)(row0 + rl + r) * N + col] = v;
                }
            }
        }
    }
}

extern "C" void kernel_launch(void* const* d_in, const int* in_sizes, int n_in,
                              void* d_out, int out_size, void* d_ws, size_t ws_size,
                              hipStream_t stream) {
    const float* x       = (const float*)d_in[0];  // [T,H]
    const float* gate_w  = (const float*)d_in[1];  // [E,H]
    const float* w_gate  = (const float*)d_in[2];  // [E,H,I]
    const float* w_up    = (const float*)d_in[3];  // [E,H,I]
    const float* w_down  = (const float*)d_in[4];  // [E,I,H]
    const float* sw_gate = (const float*)d_in[5];  // [H,IS]
    const float* sw_up   = (const float*)d_in[6];  // [H,IS]
    const float* sw_down = (const float*)d_in[7];  // [IS,H]
    float* y = (float*)d_out;                      // [T,H]

    char* p = (char*)d_ws;
    auto alloc = [&](size_t bytes) -> void* {
        void* r = (void*)p;
        p += (bytes + 255) & ~(size_t)255;
        return r;
    };
    unsigned short* xb   = (unsigned short*)alloc((size_t)T_TOK * H_DIM * 2);
    unsigned short* wgT  = (unsigned short*)alloc((size_t)E_NUM * I_DIM * H_DIM * 2);
    unsigned short* wuT  = (unsigned short*)alloc((size_t)E_NUM * I_DIM * H_DIM * 2);
    unsigned short* wdT  = (unsigned short*)alloc((size_t)E_NUM * H_DIM * I_DIM * 2);
    unsigned short* sgT  = (unsigned short*)alloc((size_t)IS_DIM * H_DIM * 2);
    unsigned short* suT  = (unsigned short*)alloc((size_t)IS_DIM * H_DIM * 2);
    unsigned short* sdT  = (unsigned short*)alloc((size_t)H_DIM * IS_DIM * 2);
    unsigned short* mid  = (unsigned short*)alloc((size_t)E_NUM * CAP * I_DIM * 2);
    unsigned short* smid = (unsigned short*)alloc((size_t)T_TOK * IS_DIM * 2);
    int*   counts = (int*)alloc(E_NUM * 4);
    int*   buf    = (int*)alloc(E_NUM * CAP * 4);
    float* wbuf   = (float*)alloc(E_NUM * CAP * 4);

    hipMemsetAsync(counts, 0, E_NUM * 4, stream);
    hipMemsetAsync(buf, 0, E_NUM * CAP * 4, stream);    // token 0: safe gather target
    hipMemsetAsync(wbuf, 0, E_NUM * CAP * 4, stream);

    // conversions
    cvt_x<<<(T_TOK * H_DIM / 4 + 255) / 256, 256, 0, stream>>>(x, xb, T_TOK * H_DIM / 4);
    tr_cast<<<dim3(I_DIM / 64, H_DIM / 64, E_NUM), 256, 0, stream>>>(w_gate, wgT, H_DIM, I_DIM);
    tr_cast<<<dim3(I_DIM / 64, H_DIM / 64, E_NUM), 256, 0, stream>>>(w_up, wuT, H_DIM, I_DIM);
    tr_cast<<<dim3(H_DIM / 64, I_DIM / 64, E_NUM), 256, 0, stream>>>(w_down, wdT, I_DIM, H_DIM);
    tr_cast<<<dim3(IS_DIM / 64, H_DIM / 64, 1), 256, 0, stream>>>(sw_gate, sgT, H_DIM, IS_DIM);
    tr_cast<<<dim3(IS_DIM / 64, H_DIM / 64, 1), 256, 0, stream>>>(sw_up, suT, H_DIM, IS_DIM);
    tr_cast<<<dim3(H_DIM / 64, IS_DIM / 64, 1), 256, 0, stream>>>(sw_down, sdT, IS_DIM, H_DIM);

    // gating + dispatch
    gate_topk<<<T_TOK, 256, 0, stream>>>(x, gate_w, counts, buf, wbuf);

    // routed gate+up -> mid
    gemm_gateup<<<dim3(I_DIM / 128, CAP / 128, E_NUM), 256, 0, stream>>>(
        xb, wgT, wuT, mid, buf, counts, H_DIM, I_DIM, (long long)CAP * I_DIM);
    // shared gate+up -> smid
    gemm_gateup<<<dim3(IS_DIM / 128, T_TOK / 128, 1), 256, 0, stream>>>(
        xb, sgT, suT, smid, nullptr, nullptr, H_DIM, IS_DIM, 0);
    // shared down: writes y fully (must precede routed atomics)
    gemm_down<<<dim3(H_DIM / 128, T_TOK / 128, 1), 256, 0, stream>>>(
        smid, sdT, y, nullptr, nullptr, nullptr, IS_DIM, H_DIM, 0, 0);
    // routed down: scaled atomic scatter-add into y
    gemm_down<<<dim3(H_DIM / 128, CAP / 128, E_NUM), 256, 0, stream>>>(
        mid, wdT, y, buf, counts, wbuf, I_DIM, H_DIM,
        (long long)CAP * I_DIM, (long long)H_DIM * I_DIM);
}

// Round 2
// 2776.001 us; speedup vs baseline: 1.0198x; 1.0198x over previous
//
#include <hip/hip_runtime.h>
#include <hip/hip_bf16.h>

// FlashDeepseekLayer: MoE (16 experts, top-4, CAP=1024) + shared SwiGLU.
// R1: replaced atomic scatter combine (3.76 GB amplified writes, MfmaUtil 2%)
// with dense bf16 eout + per-token gather combine.

#define T_TOK 2048
#define H_DIM 2048
#define E_NUM 16
#define K_TOP 4
#define I_DIM 1408
#define IS_DIM 2816
#define CAP 1024

#define BM 128
#define BN 128
#define BK 32
#define LDT 40  // padded LDS row stride (elements); 80 B = 5*16 B

typedef __attribute__((ext_vector_type(8))) short short8;
typedef __attribute__((ext_vector_type(4))) float floatx4;

__device__ __forceinline__ unsigned short f2bf(float f) {
    union { float f; unsigned u; } v; v.f = f;
    unsigned r = v.u + 0x7FFF + ((v.u >> 16) & 1);   // RNE
    return (unsigned short)(r >> 16);
}
__device__ __forceinline__ float bf2f(unsigned short u) {
    union { unsigned u; float f; } v; v.u = ((unsigned)u) << 16;
    return v.f;
}

// ---------------- x fp32 -> bf16 (layout preserved) ----------------
__global__ void cvt_x(const float* __restrict__ in, unsigned short* __restrict__ out, int n4) {
    int i = blockIdx.x * 256 + threadIdx.x;
    if (i >= n4) return;
    float4 v = ((const float4*)in)[i];
    ushort4 o;
    o.x = f2bf(v.x); o.y = f2bf(v.y); o.z = f2bf(v.z); o.w = f2bf(v.w);
    ((ushort4*)out)[i] = o;
}

// ---------------- transpose + cast: in [R][C] fp32 -> out [C][R] bf16 ----------------
__global__ void tr_cast(const float* __restrict__ in, unsigned short* __restrict__ out,
                        int R, int C) {
    __shared__ float tile[64][65];
    size_t boff = (size_t)blockIdx.z * R * C;
    in += boff; out += boff;
    int c0 = blockIdx.x * 64, r0 = blockIdx.y * 64;
    int tc = threadIdx.x & 63, tr4 = threadIdx.x >> 6;  // 0..3
    for (int p = 0; p < 16; ++p) {
        int r = tr4 + p * 4;
        tile[r][tc] = in[(size_t)(r0 + r) * C + c0 + tc];
    }
    __syncthreads();
    for (int p = 0; p < 16; ++p) {
        int rw = tr4 + p * 4;  // output row within tile (= original col)
        out[(size_t)(c0 + rw) * R + r0 + tc] = f2bf(tile[tc][rw]);
    }
}

// ---------------- gating: fp32 scores, softmax top-4, dispatch + slot record ----------
__global__ void gate_topk(const float* __restrict__ x, const float* __restrict__ gw,
                          int* __restrict__ counts, int* __restrict__ buf,
                          int* __restrict__ slotIdx, float* __restrict__ slotW) {
    int t = blockIdx.x;
    int tid = threadIdx.x, w = tid >> 6, lane = tid & 63;
    __shared__ float sc[E_NUM];
    const float* xr = x + (size_t)t * H_DIM;
    for (int e4 = 0; e4 < 4; ++e4) {
        int e = w * 4 + e4;
        const float* gr = gw + (size_t)e * H_DIM;
        float s = 0.f;
        for (int h = lane; h < H_DIM; h += 64) s += xr[h] * gr[h];
        for (int off = 32; off; off >>= 1) s += __shfl_xor(s, off);
        if (lane == 0) sc[e] = s;
    }
    __syncthreads();
    if (tid == 0) {
        int idx[4]; float lv[4]; unsigned taken = 0;
        for (int k = 0; k < 4; ++k) {
            int bi = 0; float bv = -1e30f;
            for (int e = 0; e < E_NUM; ++e)
                if (!((taken >> e) & 1) && sc[e] > bv) { bv = sc[e]; bi = e; }
            taken |= 1u << bi; idx[k] = bi; lv[k] = bv;
        }
        float m = lv[0], ws[4], s = 0.f;
        for (int k = 0; k < 4; ++k) { ws[k] = expf(lv[k] - m); s += ws[k]; }
        float inv = 1.f / s;
        for (int k = 0; k < 4; ++k) {
            int e = idx[k];
            int r = atomicAdd(&counts[e], 1);
            int slot = -1;
            if (r < CAP) { buf[e * CAP + r] = t; slot = e * CAP + r; }
            slotIdx[t * 4 + k] = slot;
            slotW[t * 4 + k] = ws[k] * inv;
        }
    }
}

// ---------------- fused gate+up GEMM with SwiGLU epilogue -> bf16 mid ----------------
// A: bf16 [*, K] rows (gathered via buf if non-null). Bg/Bu: bf16 [z][N][K].
// out: bf16 [z][Mrows][N].
__global__ __launch_bounds__(256, 2)
void gemm_gateup(const unsigned short* __restrict__ A,
                 const unsigned short* __restrict__ Bg,
                 const unsigned short* __restrict__ Bu,
                 unsigned short* __restrict__ out,
                 const int* __restrict__ buf, const int* __restrict__ counts,
                 int K, int N, long long outBatchStride) {
    int e = blockIdx.z;
    int col0 = blockIdx.x * BN, row0 = blockIdx.y * BM;
    if (counts) { if (row0 >= counts[e]) return; }
    const unsigned short* bgB = Bg + (size_t)e * N * K;
    const unsigned short* buB = Bu + (size_t)e * N * K;
    unsigned short* outB = out + (size_t)e * outBatchStride;

    __shared__ unsigned short lA[BM * LDT], lG[BM * LDT], lU[BM * LDT];

    int tid = threadIdx.x;
    const unsigned short *ap[2], *gp[2], *up[2];
    int wrOff[2];
    for (int i = 0; i < 2; ++i) {
        int c = tid + i * 256, r = c >> 2, s = c & 3;
        int grow = buf ? buf[e * CAP + row0 + r] : (row0 + r);
        ap[i] = A + (size_t)grow * K + s * 8;
        gp[i] = bgB + (size_t)(col0 + r) * K + s * 8;
        up[i] = buB + (size_t)(col0 + r) * K + s * 8;
        wrOff[i] = r * LDT + s * 8;
    }

    int w = tid >> 6, lane = tid & 63;
    int wm = (w >> 1) * 64, wn = (w & 1) * 64;
    int lq = lane >> 4, lr = lane & 15;

    floatx4 accg[4][4], accu[4][4];
    for (int i = 0; i < 4; ++i)
        for (int j = 0; j < 4; ++j) {
            accg[i][j] = (floatx4){0.f, 0.f, 0.f, 0.f};
            accu[i][j] = (floatx4){0.f, 0.f, 0.f, 0.f};
        }

    for (int k0 = 0; k0 < K; k0 += BK) {
        int4 av[2], gv[2], uv[2];
        for (int i = 0; i < 2; ++i) {
            av[i] = *(const int4*)(ap[i] + k0);
            gv[i] = *(const int4*)(gp[i] + k0);
            uv[i] = *(const int4*)(up[i] + k0);
        }
        __syncthreads();
        for (int i = 0; i < 2; ++i) {
            *(int4*)(lA + wrOff[i]) = av[i];
            *(int4*)(lG + wrOff[i]) = gv[i];
            *(int4*)(lU + wrOff[i]) = uv[i];
        }
        __syncthreads();
        short8 aF[4], gF[4], uF[4];
        for (int i = 0; i < 4; ++i)
            aF[i] = *(const short8*)(lA + (wm + i * 16 + lr) * LDT + lq * 8);
        for (int j = 0; j < 4; ++j) {
            gF[j] = *(const short8*)(lG + (wn + j * 16 + lr) * LDT + lq * 8);
            uF[j] = *(const short8*)(lU + (wn + j * 16 + lr) * LDT + lq * 8);
        }
        for (int i = 0; i < 4; ++i)
            for (int j = 0; j < 4; ++j) {
                accg[i][j] = __builtin_amdgcn_mfma_f32_16x16x32_bf16(aF[i], gF[j], accg[i][j], 0, 0, 0);
                accu[i][j] = __builtin_amdgcn_mfma_f32_16x16x32_bf16(aF[i], uF[j], accu[i][j], 0, 0, 0);
            }
    }
    for (int i = 0; i < 4; ++i) {
        int rbase = row0 + wm + i * 16 + lq * 4;
        for (int j = 0; j < 4; ++j) {
            int col = col0 + wn + j * 16 + lr;
            for (int r = 0; r < 4; ++r) {
                float g = accg[i][j][r], u = accu[i][j][r];
                float mval = g / (1.f + __expf(-g)) * u;  // silu(g)*u
                outB[(size_t)(rbase + r) * N + col] = f2bf(mval);
            }
        }
    }
}

// ---------------- down GEMM: dense store, fp32 (shared->y) or bf16 (routed->eout) ----
// A: bf16 [z][Mrows][K]. B: bf16 [z][N][K].
__global__ __launch_bounds__(256, 2)
void gemm_down(const unsigned short* __restrict__ A,
               const unsigned short* __restrict__ B,
               float* __restrict__ yF,
               unsigned short* __restrict__ outBf,
               const int* __restrict__ counts,
               int K, int N, long long aBatchStride, long long bBatchStride,
               long long outBatchStride) {
    int e = blockIdx.z;
    int col0 = blockIdx.x * BN, row0 = blockIdx.y * BM;
    if (counts) { if (row0 >= counts[e]) return; }
    const unsigned short* aB = A + (size_t)e * aBatchStride;
    const unsigned short* bB = B + (size_t)e * bBatchStride;

    __shared__ unsigned short lA[BM * LDT], lB[BM * LDT];

    int tid = threadIdx.x;
    const unsigned short *ap[2], *bp[2];
    int wrOff[2];
    for (int i = 0; i < 2; ++i) {
        int c = tid + i * 256, r = c >> 2, s = c & 3;
        ap[i] = aB + (size_t)(row0 + r) * K + s * 8;
        bp[i] = bB + (size_t)(col0 + r) * K + s * 8;
        wrOff[i] = r * LDT + s * 8;
    }
    int w = tid >> 6, lane = tid & 63;
    int wm = (w >> 1) * 64, wn = (w & 1) * 64;
    int lq = lane >> 4, lr = lane & 15;

    floatx4 acc[4][4];
    for (int i = 0; i < 4; ++i)
        for (int j = 0; j < 4; ++j) acc[i][j] = (floatx4){0.f, 0.f, 0.f, 0.f};

    for (int k0 = 0; k0 < K; k0 += BK) {
        int4 av[2], bv[2];
        for (int i = 0; i < 2; ++i) {
            av[i] = *(const int4*)(ap[i] + k0);
            bv[i] = *(const int4*)(bp[i] + k0);
        }
        __syncthreads();
        for (int i = 0; i < 2; ++i) {
            *(int4*)(lA + wrOff[i]) = av[i];
            *(int4*)(lB + wrOff[i]) = bv[i];
        }
        __syncthreads();
        short8 aF[4], bF[4];
        for (int i = 0; i < 4; ++i)
            aF[i] = *(const short8*)(lA + (wm + i * 16 + lr) * LDT + lq * 8);
        for (int j = 0; j < 4; ++j)
            bF[j] = *(const short8*)(lB + (wn + j * 16 + lr) * LDT + lq * 8);
        for (int i = 0; i < 4; ++i)
            for (int j = 0; j < 4; ++j)
                acc[i][j] = __builtin_amdgcn_mfma_f32_16x16x32_bf16(aF[i], bF[j], acc[i][j], 0, 0, 0);
    }

    for (int i = 0; i < 4; ++i) {
        int rl = wm + i * 16 + lq * 4;
        for (int j = 0; j < 4; ++j) {
            int col = col0 + wn + j * 16 + lr;
            for (int r = 0; r < 4; ++r) {
                float v = acc[i][j][r];
                if (outBf) {
                    outBf[(size_t)e * outBatchStride + (size_t)(row0 + rl + r) * N + col] = f2bf(v);
                } else {
                    yF[(size_t)(row0 + rl + r) * N + col] = v;
                }
            }
        }
    }
}

// ---------------- combine: y[t] += sum_k w_k * eout[slot_k] ----------------
__global__ void combine(const unsigned short* __restrict__ eout,
                        const int* __restrict__ slotIdx,
                        const float* __restrict__ slotW,
                        float* __restrict__ y) {
    int t = blockIdx.x;
    int c = threadIdx.x * 8;  // 256 threads * 8 = 2048 = H
    int4 s4 = *(const int4*)(slotIdx + t * 4);
    float4 w4 = *(const float4*)(slotW + t * 4);
    int slots[4] = {s4.x, s4.y, s4.z, s4.w};
    float ws[4] = {w4.x, w4.y, w4.z, w4.w};
    float acc[8];
    float4 y0 = *(const float4*)(y + (size_t)t * H_DIM + c);
    float4 y1 = *(const float4*)(y + (size_t)t * H_DIM + c + 4);
    acc[0] = y0.x; acc[1] = y0.y; acc[2] = y0.z; acc[3] = y0.w;
    acc[4] = y1.x; acc[5] = y1.y; acc[6] = y1.z; acc[7] = y1.w;
    for (int k = 0; k < 4; ++k) {
        if (slots[k] < 0) continue;
        ushort4 v0 = *(const ushort4*)(eout + (size_t)slots[k] * H_DIM + c);
        ushort4 v1 = *(const ushort4*)(eout + (size_t)slots[k] * H_DIM + c + 4);
        float wk = ws[k];
        acc[0] += wk * bf2f(v0.x); acc[1] += wk * bf2f(v0.y);
        acc[2] += wk * bf2f(v0.z); acc[3] += wk * bf2f(v0.w);
        acc[4] += wk * bf2f(v1.x); acc[5] += wk * bf2f(v1.y);
        acc[6] += wk * bf2f(v1.z); acc[7] += wk * bf2f(v1.w);
    }
    *(float4*)(y + (size_t)t * H_DIM + c)     = (float4){acc[0], acc[1], acc[2], acc[3]};
    *(float4*)(y + (size_t)t * H_DIM + c + 4) = (float4){acc[4], acc[5], acc[6], acc[7]};
}

extern "C" void kernel_launch(void* const* d_in, const int* in_sizes, int n_in,
                              void* d_out, int out_size, void* d_ws, size_t ws_size,
                              hipStream_t stream) {
    const float* x       = (const float*)d_in[0];  // [T,H]
    const float* gate_w  = (const float*)d_in[1];  // [E,H]
    const float* w_gate  = (const float*)d_in[2];  // [E,H,I]
    const float* w_up    = (const float*)d_in[3];  // [E,H,I]
    const float* w_down  = (const float*)d_in[4];  // [E,I,H]
    const float* sw_gate = (const float*)d_in[5];  // [H,IS]
    const float* sw_up   = (const float*)d_in[6];  // [H,IS]
    const float* sw_down = (const float*)d_in[7];  // [IS,H]
    float* y = (float*)d_out;                      // [T,H]

    char* p = (char*)d_ws;
    auto alloc = [&](size_t bytes) -> void* {
        void* r = (void*)p;
        p += (bytes + 255) & ~(size_t)255;
        return r;
    };
    unsigned short* xb   = (unsigned short*)alloc((size_t)T_TOK * H_DIM * 2);
    unsigned short* wgT  = (unsigned short*)alloc((size_t)E_NUM * I_DIM * H_DIM * 2);
    unsigned short* wuT  = (unsigned short*)alloc((size_t)E_NUM * I_DIM * H_DIM * 2);
    unsigned short* wdT  = (unsigned short*)alloc((size_t)E_NUM * H_DIM * I_DIM * 2);
    unsigned short* sgT  = (unsigned short*)alloc((size_t)IS_DIM * H_DIM * 2);
    unsigned short* suT  = (unsigned short*)alloc((size_t)IS_DIM * H_DIM * 2);
    unsigned short* sdT  = (unsigned short*)alloc((size_t)H_DIM * IS_DIM * 2);
    unsigned short* mid  = (unsigned short*)alloc((size_t)E_NUM * CAP * I_DIM * 2);
    unsigned short* smid = (unsigned short*)alloc((size_t)T_TOK * IS_DIM * 2);
    unsigned short* eout = (unsigned short*)alloc((size_t)E_NUM * CAP * H_DIM * 2);
    int*   counts  = (int*)alloc(E_NUM * 4);
    int*   buf     = (int*)alloc(E_NUM * CAP * 4);
    int*   slotIdx = (int*)alloc(T_TOK * K_TOP * 4);
    float* slotW   = (float*)alloc(T_TOK * K_TOP * 4);

    hipMemsetAsync(counts, 0, E_NUM * 4, stream);
    hipMemsetAsync(buf, 0, E_NUM * CAP * 4, stream);    // token 0: safe gather target

    // conversions
    cvt_x<<<(T_TOK * H_DIM / 4 + 255) / 256, 256, 0, stream>>>(x, xb, T_TOK * H_DIM / 4);
    tr_cast<<<dim3(I_DIM / 64, H_DIM / 64, E_NUM), 256, 0, stream>>>(w_gate, wgT, H_DIM, I_DIM);
    tr_cast<<<dim3(I_DIM / 64, H_DIM / 64, E_NUM), 256, 0, stream>>>(w_up, wuT, H_DIM, I_DIM);
    tr_cast<<<dim3(H_DIM / 64, I_DIM / 64, E_NUM), 256, 0, stream>>>(w_down, wdT, I_DIM, H_DIM);
    tr_cast<<<dim3(IS_DIM / 64, H_DIM / 64, 1), 256, 0, stream>>>(sw_gate, sgT, H_DIM, IS_DIM);
    tr_cast<<<dim3(IS_DIM / 64, H_DIM / 64, 1), 256, 0, stream>>>(sw_up, suT, H_DIM, IS_DIM);
    tr_cast<<<dim3(H_DIM / 64, IS_DIM / 64, 1), 256, 0, stream>>>(sw_down, sdT, IS_DIM, H_DIM);

    // gating + dispatch
    gate_topk<<<T_TOK, 256, 0, stream>>>(x, gate_w, counts, buf, slotIdx, slotW);

    // routed gate+up -> mid
    gemm_gateup<<<dim3(I_DIM / 128, CAP / 128, E_NUM), 256, 0, stream>>>(
        xb, wgT, wuT, mid, buf, counts, H_DIM, I_DIM, (long long)CAP * I_DIM);
    // shared gate+up -> smid
    gemm_gateup<<<dim3(IS_DIM / 128, T_TOK / 128, 1), 256, 0, stream>>>(
        xb, sgT, suT, smid, nullptr, nullptr, H_DIM, IS_DIM, 0);
    // shared down: writes y fully (dense fp32)
    gemm_down<<<dim3(H_DIM / 128, T_TOK / 128, 1), 256, 0, stream>>>(
        smid, sdT, y, nullptr, nullptr, IS_DIM, H_DIM, 0, 0, 0);
    // routed down: dense bf16 eout
    gemm_down<<<dim3(H_DIM / 128, CAP / 128, E_NUM), 256, 0, stream>>>(
        mid, wdT, nullptr, eout, counts, I_DIM, H_DIM,
        (long long)CAP * I_DIM, (long long)H_DIM * I_DIM, (long long)CAP * H_DIM);
    // combine: y[t] += sum_k w_k * eout[slot_k]
    combine<<<T_TOK, 256, 0, stream>>>(eout, slotIdx, slotW, y);
}

// Round 3
// 1157.055 us; speedup vs baseline: 2.4467x; 2.3992x over previous
//
#include <hip/hip_runtime.h>
#include <hip/hip_bf16.h>

// FlashDeepseekLayer: MoE (16 experts, top-4, CAP=1024) + shared SwiGLU.
// R2 post-mortem: WRITE_SIZE (3.86 GB) and LDS conflicts were bit-identical
// across R1/R2 epilogue change -> K-loop scratch spill was the bottleneck,
// not atomics. R3: m97 structure — global_load_lds width=16 staging (no VGPR
// round-trip, nothing live across barriers), unpadded [128][32] LDS tiles.

#define T_TOK 2048
#define H_DIM 2048
#define E_NUM 16
#define K_TOP 4
#define I_DIM 1408
#define IS_DIM 2816
#define CAP 1024

#define BM 128
#define BN 128
#define BK 32

typedef __attribute__((ext_vector_type(8))) short short8;
typedef __attribute__((ext_vector_type(4))) float floatx4;

__device__ __forceinline__ unsigned short f2bf(float f) {
    union { float f; unsigned u; } v; v.f = f;
    unsigned r = v.u + 0x7FFF + ((v.u >> 16) & 1);   // RNE
    return (unsigned short)(r >> 16);
}
__device__ __forceinline__ float bf2f(unsigned short u) {
    union { unsigned u; float f; } v; v.u = ((unsigned)u) << 16;
    return v.f;
}

// async global->LDS, 16 B per lane; lds dest = wave-uniform base + lane*16
__device__ __forceinline__ void gl_lds16(const unsigned short* g, unsigned short* l) {
    __builtin_amdgcn_global_load_lds(
        (__attribute__((address_space(1))) const unsigned int*)g,
        (__attribute__((address_space(3))) unsigned int*)l, 16, 0, 0);
}

// ---------------- x fp32 -> bf16 (layout preserved) ----------------
__global__ void cvt_x(const float* __restrict__ in, unsigned short* __restrict__ out, int n4) {
    int i = blockIdx.x * 256 + threadIdx.x;
    if (i >= n4) return;
    float4 v = ((const float4*)in)[i];
    ushort4 o;
    o.x = f2bf(v.x); o.y = f2bf(v.y); o.z = f2bf(v.z); o.w = f2bf(v.w);
    ((ushort4*)out)[i] = o;
}

// ---------------- transpose + cast: in [R][C] fp32 -> out [C][R] bf16 ----------------
__global__ void tr_cast(const float* __restrict__ in, unsigned short* __restrict__ out,
                        int R, int C) {
    __shared__ float tile[64][65];
    size_t boff = (size_t)blockIdx.z * R * C;
    in += boff; out += boff;
    int c0 = blockIdx.x * 64, r0 = blockIdx.y * 64;
    int tc = threadIdx.x & 63, tr4 = threadIdx.x >> 6;  // 0..3
    #pragma unroll
    for (int p = 0; p < 16; ++p) {
        int r = tr4 + p * 4;
        tile[r][tc] = in[(size_t)(r0 + r) * C + c0 + tc];
    }
    __syncthreads();
    #pragma unroll
    for (int p = 0; p < 16; ++p) {
        int rw = tr4 + p * 4;  // output row within tile (= original col)
        out[(size_t)(c0 + rw) * R + r0 + tc] = f2bf(tile[tc][rw]);
    }
}

// ---------------- gating: fp32 scores, softmax top-4, dispatch + slot record ----------
__global__ void gate_topk(const float* __restrict__ x, const float* __restrict__ gw,
                          int* __restrict__ counts, int* __restrict__ buf,
                          int* __restrict__ slotIdx, float* __restrict__ slotW) {
    int t = blockIdx.x;
    int tid = threadIdx.x, w = tid >> 6, lane = tid & 63;
    __shared__ float sc[E_NUM];
    const float* xr = x + (size_t)t * H_DIM;
    for (int e4 = 0; e4 < 4; ++e4) {
        int e = w * 4 + e4;
        const float* gr = gw + (size_t)e * H_DIM;
        float s = 0.f;
        for (int h = lane; h < H_DIM; h += 64) s += xr[h] * gr[h];
        for (int off = 32; off; off >>= 1) s += __shfl_xor(s, off);
        if (lane == 0) sc[e] = s;
    }
    __syncthreads();
    if (tid == 0) {
        int idx[4]; float lv[4]; unsigned taken = 0;
        for (int k = 0; k < 4; ++k) {
            int bi = 0; float bv = -1e30f;
            for (int e = 0; e < E_NUM; ++e)
                if (!((taken >> e) & 1) && sc[e] > bv) { bv = sc[e]; bi = e; }
            taken |= 1u << bi; idx[k] = bi; lv[k] = bv;
        }
        float m = lv[0], ws[4], s = 0.f;
        for (int k = 0; k < 4; ++k) { ws[k] = expf(lv[k] - m); s += ws[k]; }
        float inv = 1.f / s;
        for (int k = 0; k < 4; ++k) {
            int e = idx[k];
            int r = atomicAdd(&counts[e], 1);
            int slot = -1;
            if (r < CAP) { buf[e * CAP + r] = t; slot = e * CAP + r; }
            slotIdx[t * 4 + k] = slot;
            slotW[t * 4 + k] = ws[k] * inv;
        }
    }
}

// ---------------- fused gate+up GEMM with SwiGLU epilogue -> bf16 mid ----------------
// A: bf16 [*, K] rows (gathered via buf if non-null). Bg/Bu: bf16 [z][N][K].
// out: bf16 [z][Mrows][N]. m97-style staging.
__global__ __launch_bounds__(256, 2)
void gemm_gateup(const unsigned short* __restrict__ A,
                 const unsigned short* __restrict__ Bg,
                 const unsigned short* __restrict__ Bu,
                 unsigned short* __restrict__ out,
                 const int* __restrict__ buf, const int* __restrict__ counts,
                 int K, int N, long long outBatchStride) {
    int e = blockIdx.z;
    int col0 = blockIdx.x * BN, row0 = blockIdx.y * BM;
    if (counts && row0 >= counts[e]) return;
    const unsigned short* bgB = Bg + (size_t)e * N * K;
    const unsigned short* buB = Bu + (size_t)e * N * K;
    unsigned short* outB = out + (size_t)e * outBatchStride;

    __shared__ __attribute__((aligned(16))) unsigned short lA[BM * BK];
    __shared__ __attribute__((aligned(16))) unsigned short lG[BM * BK];
    __shared__ __attribute__((aligned(16))) unsigned short lU[BM * BK];

    int tid = threadIdx.x, w = tid >> 6, lane = tid & 63;
    // staging: 8 chunks of 16 rows x 64 B; wave w stages chunks {2w, 2w+1};
    // lane l -> row chunk*16 + l/4, k-offset (l&3)*8 elems (16 B)
    const unsigned short *aP[2], *gP[2], *uP[2];
    unsigned short *lAp[2], *lGp[2], *lUp[2];
    #pragma unroll
    for (int c = 0; c < 2; ++c) {
        int chunk = 2 * w + c;
        int row = chunk * 16 + (lane >> 2);
        int koff = (lane & 3) * 8;
        int arow = buf ? buf[e * CAP + row0 + row] : (row0 + row);
        aP[c] = A + (size_t)arow * K + koff;
        gP[c] = bgB + (size_t)(col0 + row) * K + koff;
        uP[c] = buB + (size_t)(col0 + row) * K + koff;
        lAp[c] = lA + chunk * 512;   // 1024 B per chunk
        lGp[c] = lG + chunk * 512;
        lUp[c] = lU + chunk * 512;
    }

    int wm = (w >> 1) * 64, wn = (w & 1) * 64;
    int lq = lane >> 4, lr = lane & 15;

    floatx4 accg[4][4], accu[4][4];
    #pragma unroll
    for (int i = 0; i < 4; ++i)
        #pragma unroll
        for (int j = 0; j < 4; ++j) {
            accg[i][j] = (floatx4){0.f, 0.f, 0.f, 0.f};
            accu[i][j] = (floatx4){0.f, 0.f, 0.f, 0.f};
        }

    for (int k0 = 0; k0 < K; k0 += BK) {
        #pragma unroll
        for (int c = 0; c < 2; ++c) {
            gl_lds16(aP[c] + k0, lAp[c]);
            gl_lds16(gP[c] + k0, lGp[c]);
            gl_lds16(uP[c] + k0, lUp[c]);
        }
        __syncthreads();   // drains vmcnt -> tiles resident in LDS
        short8 aF[4], gF[4], uF[4];
        #pragma unroll
        for (int i = 0; i < 4; ++i) {
            aF[i] = *(const short8*)(lA + (wm + i * 16 + lr) * BK + lq * 8);
            gF[i] = *(const short8*)(lG + (wn + i * 16 + lr) * BK + lq * 8);
            uF[i] = *(const short8*)(lU + (wn + i * 16 + lr) * BK + lq * 8);
        }
        __syncthreads();   // all waves done reading; next staging may overwrite
        #pragma unroll
        for (int i = 0; i < 4; ++i)
            #pragma unroll
            for (int j = 0; j < 4; ++j) {
                accg[i][j] = __builtin_amdgcn_mfma_f32_16x16x32_bf16(aF[i], gF[j], accg[i][j], 0, 0, 0);
                accu[i][j] = __builtin_amdgcn_mfma_f32_16x16x32_bf16(aF[i], uF[j], accu[i][j], 0, 0, 0);
            }
    }
    #pragma unroll
    for (int i = 0; i < 4; ++i) {
        int rbase = row0 + wm + i * 16 + lq * 4;
        #pragma unroll
        for (int j = 0; j < 4; ++j) {
            int col = col0 + wn + j * 16 + lr;
            #pragma unroll
            for (int r = 0; r < 4; ++r) {
                float g = accg[i][j][r], u = accu[i][j][r];
                float mval = g / (1.f + __expf(-g)) * u;  // silu(g)*u
                outB[(size_t)(rbase + r) * N + col] = f2bf(mval);
            }
        }
    }
}

// ---------------- down GEMM: dense store, fp32 (shared->y) or bf16 (routed->eout) ----
// A: bf16 [z][Mrows][K]. B: bf16 [z][N][K]. m97-style staging.
__global__ __launch_bounds__(256, 2)
void gemm_down(const unsigned short* __restrict__ A,
               const unsigned short* __restrict__ B,
               float* __restrict__ yF,
               unsigned short* __restrict__ outBf,
               const int* __restrict__ counts,
               int K, int N, long long aBatchStride, long long bBatchStride,
               long long outBatchStride) {
    int e = blockIdx.z;
    int col0 = blockIdx.x * BN, row0 = blockIdx.y * BM;
    if (counts && row0 >= counts[e]) return;
    const unsigned short* aB = A + (size_t)e * aBatchStride;
    const unsigned short* bB = B + (size_t)e * bBatchStride;

    __shared__ __attribute__((aligned(16))) unsigned short lA[BM * BK];
    __shared__ __attribute__((aligned(16))) unsigned short lB[BM * BK];

    int tid = threadIdx.x, w = tid >> 6, lane = tid & 63;
    const unsigned short *aP[2], *bP[2];
    unsigned short *lAp[2], *lBp[2];
    #pragma unroll
    for (int c = 0; c < 2; ++c) {
        int chunk = 2 * w + c;
        int row = chunk * 16 + (lane >> 2);
        int koff = (lane & 3) * 8;
        aP[c] = aB + (size_t)(row0 + row) * K + koff;
        bP[c] = bB + (size_t)(col0 + row) * K + koff;
        lAp[c] = lA + chunk * 512;
        lBp[c] = lB + chunk * 512;
    }

    int wm = (w >> 1) * 64, wn = (w & 1) * 64;
    int lq = lane >> 4, lr = lane & 15;

    floatx4 acc[4][4];
    #pragma unroll
    for (int i = 0; i < 4; ++i)
        #pragma unroll
        for (int j = 0; j < 4; ++j) acc[i][j] = (floatx4){0.f, 0.f, 0.f, 0.f};

    for (int k0 = 0; k0 < K; k0 += BK) {
        #pragma unroll
        for (int c = 0; c < 2; ++c) {
            gl_lds16(aP[c] + k0, lAp[c]);
            gl_lds16(bP[c] + k0, lBp[c]);
        }
        __syncthreads();
        short8 aF[4], bF[4];
        #pragma unroll
        for (int i = 0; i < 4; ++i) {
            aF[i] = *(const short8*)(lA + (wm + i * 16 + lr) * BK + lq * 8);
            bF[i] = *(const short8*)(lB + (wn + i * 16 + lr) * BK + lq * 8);
        }
        __syncthreads();
        #pragma unroll
        for (int i = 0; i < 4; ++i)
            #pragma unroll
            for (int j = 0; j < 4; ++j)
                acc[i][j] = __builtin_amdgcn_mfma_f32_16x16x32_bf16(aF[i], bF[j], acc[i][j], 0, 0, 0);
    }

    #pragma unroll
    for (int i = 0; i < 4; ++i) {
        int rl = wm + i * 16 + lq * 4;
        #pragma unroll
        for (int j = 0; j < 4; ++j) {
            int col = col0 + wn + j * 16 + lr;
            #pragma unroll
            for (int r = 0; r < 4; ++r) {
                float v = acc[i][j][r];
                if (outBf) {
                    outBf[(size_t)e * outBatchStride + (size_t)(row0 + rl + r) * N + col] = f2bf(v);
                } else {
                    yF[(size_t)(row0 + rl + r) * N + col] = v;
                }
            }
        }
    }
}

// ---------------- combine: y[t] += sum_k w_k * eout[slot_k] ----------------
__global__ void combine(const unsigned short* __restrict__ eout,
                        const int* __restrict__ slotIdx,
                        const float* __restrict__ slotW,
                        float* __restrict__ y) {
    int t = blockIdx.x;
    int c = threadIdx.x * 8;  // 256 threads * 8 = 2048 = H
    int4 s4 = *(const int4*)(slotIdx + t * 4);
    float4 w4 = *(const float4*)(slotW + t * 4);
    int slots[4] = {s4.x, s4.y, s4.z, s4.w};
    float ws[4] = {w4.x, w4.y, w4.z, w4.w};
    float acc[8];
    float4 y0 = *(const float4*)(y + (size_t)t * H_DIM + c);
    float4 y1 = *(const float4*)(y + (size_t)t * H_DIM + c + 4);
    acc[0] = y0.x; acc[1] = y0.y; acc[2] = y0.z; acc[3] = y0.w;
    acc[4] = y1.x; acc[5] = y1.y; acc[6] = y1.z; acc[7] = y1.w;
    #pragma unroll
    for (int k = 0; k < 4; ++k) {
        if (slots[k] < 0) continue;
        ushort4 v0 = *(const ushort4*)(eout + (size_t)slots[k] * H_DIM + c);
        ushort4 v1 = *(const ushort4*)(eout + (size_t)slots[k] * H_DIM + c + 4);
        float wk = ws[k];
        acc[0] += wk * bf2f(v0.x); acc[1] += wk * bf2f(v0.y);
        acc[2] += wk * bf2f(v0.z); acc[3] += wk * bf2f(v0.w);
        acc[4] += wk * bf2f(v1.x); acc[5] += wk * bf2f(v1.y);
        acc[6] += wk * bf2f(v1.z); acc[7] += wk * bf2f(v1.w);
    }
    *(float4*)(y + (size_t)t * H_DIM + c)     = (float4){acc[0], acc[1], acc[2], acc[3]};
    *(float4*)(y + (size_t)t * H_DIM + c + 4) = (float4){acc[4], acc[5], acc[6], acc[7]};
}

extern "C" void kernel_launch(void* const* d_in, const int* in_sizes, int n_in,
                              void* d_out, int out_size, void* d_ws, size_t ws_size,
                              hipStream_t stream) {
    const float* x       = (const float*)d_in[0];  // [T,H]
    const float* gate_w  = (const float*)d_in[1];  // [E,H]
    const float* w_gate  = (const float*)d_in[2];  // [E,H,I]
    const float* w_up    = (const float*)d_in[3];  // [E,H,I]
    const float* w_down  = (const float*)d_in[4];  // [E,I,H]
    const float* sw_gate = (const float*)d_in[5];  // [H,IS]
    const float* sw_up   = (const float*)d_in[6];  // [H,IS]
    const float* sw_down = (const float*)d_in[7];  // [IS,H]
    float* y = (float*)d_out;                      // [T,H]

    char* p = (char*)d_ws;
    auto alloc = [&](size_t bytes) -> void* {
        void* r = (void*)p;
        p += (bytes + 255) & ~(size_t)255;
        return r;
    };
    unsigned short* xb   = (unsigned short*)alloc((size_t)T_TOK * H_DIM * 2);
    unsigned short* wgT  = (unsigned short*)alloc((size_t)E_NUM * I_DIM * H_DIM * 2);
    unsigned short* wuT  = (unsigned short*)alloc((size_t)E_NUM * I_DIM * H_DIM * 2);
    unsigned short* wdT  = (unsigned short*)alloc((size_t)E_NUM * H_DIM * I_DIM * 2);
    unsigned short* sgT  = (unsigned short*)alloc((size_t)IS_DIM * H_DIM * 2);
    unsigned short* suT  = (unsigned short*)alloc((size_t)IS_DIM * H_DIM * 2);
    unsigned short* sdT  = (unsigned short*)alloc((size_t)H_DIM * IS_DIM * 2);
    unsigned short* mid  = (unsigned short*)alloc((size_t)E_NUM * CAP * I_DIM * 2);
    unsigned short* smid = (unsigned short*)alloc((size_t)T_TOK * IS_DIM * 2);
    unsigned short* eout = (unsigned short*)alloc((size_t)E_NUM * CAP * H_DIM * 2);
    int*   counts  = (int*)alloc(E_NUM * 4);
    int*   buf     = (int*)alloc(E_NUM * CAP * 4);
    int*   slotIdx = (int*)alloc(T_TOK * K_TOP * 4);
    float* slotW   = (float*)alloc(T_TOK * K_TOP * 4);

    hipMemsetAsync(counts, 0, E_NUM * 4, stream);
    hipMemsetAsync(buf, 0, E_NUM * CAP * 4, stream);    // token 0: safe gather target

    // conversions
    cvt_x<<<(T_TOK * H_DIM / 4 + 255) / 256, 256, 0, stream>>>(x, xb, T_TOK * H_DIM / 4);
    tr_cast<<<dim3(I_DIM / 64, H_DIM / 64, E_NUM), 256, 0, stream>>>(w_gate, wgT, H_DIM, I_DIM);
    tr_cast<<<dim3(I_DIM / 64, H_DIM / 64, E_NUM), 256, 0, stream>>>(w_up, wuT, H_DIM, I_DIM);
    tr_cast<<<dim3(H_DIM / 64, I_DIM / 64, E_NUM), 256, 0, stream>>>(w_down, wdT, I_DIM, H_DIM);
    tr_cast<<<dim3(IS_DIM / 64, H_DIM / 64, 1), 256, 0, stream>>>(sw_gate, sgT, H_DIM, IS_DIM);
    tr_cast<<<dim3(IS_DIM / 64, H_DIM / 64, 1), 256, 0, stream>>>(sw_up, suT, H_DIM, IS_DIM);
    tr_cast<<<dim3(H_DIM / 64, IS_DIM / 64, 1), 256, 0, stream>>>(sw_down, sdT, IS_DIM, H_DIM);

    // gating + dispatch
    gate_topk<<<T_TOK, 256, 0, stream>>>(x, gate_w, counts, buf, slotIdx, slotW);

    // routed gate+up -> mid
    gemm_gateup<<<dim3(I_DIM / 128, CAP / 128, E_NUM), 256, 0, stream>>>(
        xb, wgT, wuT, mid, buf, counts, H_DIM, I_DIM, (long long)CAP * I_DIM);
    // shared gate+up -> smid
    gemm_gateup<<<dim3(IS_DIM / 128, T_TOK / 128, 1), 256, 0, stream>>>(
        xb, sgT, suT, smid, nullptr, nullptr, H_DIM, IS_DIM, 0);
    // shared down: writes y fully (dense fp32)
    gemm_down<<<dim3(H_DIM / 128, T_TOK / 128, 1), 256, 0, stream>>>(
        smid, sdT, y, nullptr, nullptr, IS_DIM, H_DIM, 0, 0, 0);
    // routed down: dense bf16 eout
    gemm_down<<<dim3(H_DIM / 128, CAP / 128, E_NUM), 256, 0, stream>>>(
        mid, wdT, nullptr, eout, counts, I_DIM, H_DIM,
        (long long)CAP * I_DIM, (long long)H_DIM * I_DIM, (long long)CAP * H_DIM);
    // combine: y[t] += sum_k w_k * eout[slot_k]
    combine<<<T_TOK, 256, 0, stream>>>(eout, slotIdx, slotW, y);
}